// Round 4
// baseline (321.120 us; speedup 1.0000x reference)
//
#include <hip/hip_runtime.h>

// EVI fused kernel, round 4:
// - 4 threads co-own one float4 voxel group; each owns 16 of 64 channels.
// - Scan de-dup across chunk-threads (each thread scans one vec element).
// - NEW: redistribute via raw ds_bpermute (register-only; kills the 16KB LDS
//   scratch + bank conflicts that HIP's variable-lane __shfl generated).
// - NEW: 2 voxel groups per thread, software-pipelined: B's loads are issued
//   while A is consumed/computed, so HBM stays busy during the scan phase.
// - Non-temporal stores keep `out` from evicting x out of the 256 MB L3.

constexpr int kInCh    = 64;
constexpr int kCls     = 4;
constexpr int kProto   = 20;
constexpr long kSpatial = 64L * 64L * 64L;   // 262144, D contiguous
constexpr int kVec     = 4;                   // float4 voxels per group
constexpr int kChunk   = 16;                  // channels per thread

typedef float f32x4 __attribute__((ext_vector_type(4)));

__device__ __forceinline__ float lane_bcast(float v, int srcLane) {
    return __int_as_float(__builtin_amdgcn_ds_bpermute(srcLane << 2, __float_as_int(v)));
}

__global__ __launch_bounds__(256, 4) void evi_fused_kernel(
    const float* __restrict__ x,
    const float* __restrict__ w_to,    // (CLS, IN_CH)
    const float* __restrict__ b_to,    // (CLS,)
    const float* __restrict__ w_from,  // (IN_CH, CLS)
    const float* __restrict__ b_from,  // (IN_CH,)
    const float* __restrict__ Wm,      // (PROTO, CLS)
    const float* __restrict__ BETA,    // (PROTO, CLS)
    const float* __restrict__ alpha,   // (PROTO, 1)
    const float* __restrict__ gamma,   // (PROTO, 1)
    float* __restrict__ out)
{
    __shared__ float s_wt[kCls * kInCh];   // w_to[o][c]
    __shared__ float s_wf[kInCh * kCls];   // w_from[i][c]
    __shared__ float s_bf[kInCh];
    __shared__ float s_bto[kCls];
    __shared__ float s_W[kProto][kCls];
    __shared__ float s_U[kProto][kCls];
    __shared__ float s_ap[kProto];
    __shared__ float s_g2[kProto];

    const int t = threadIdx.x;

    // ---- stage weights / per-proto params into LDS (once per block) ----
    s_wt[t] = w_to[t];
    s_wf[t] = w_from[t];
    if (t < kInCh) s_bf[t] = b_from[t];
    if (t < kCls)  s_bto[t] = b_to[t];
    if (t < kProto) {
        float bsq[kCls];
        float sum = 0.f;
        #pragma unroll
        for (int c = 0; c < kCls; ++c) {
            const float bb = BETA[t * kCls + c];
            bsq[c] = bb * bb;
            sum += bsq[c];
        }
        const float inv = 1.0f / sum;
        #pragma unroll
        for (int c = 0; c < kCls; ++c) {
            s_U[t][c] = bsq[c] * inv;
            s_W[t][c] = Wm[t * kCls + c];
        }
        s_ap[t] = 0.99f / (1.0f + expf(-alpha[t]));
        const float g = gamma[t];
        s_g2[t] = g * g;
    }
    __syncthreads();

    // ---- lane decomposition: each wave handles 32 voxel groups (A:16, B:16) ----
    const int tid   = blockIdx.x * blockDim.x + t;
    const int wave  = tid >> 6;
    const int lane  = tid & 63;
    const int chunk = lane >> 4;                 // channels [chunk*16, chunk*16+16)
    const int sub   = lane & 15;
    const int c0    = chunk * kChunk;

    const int vgPerBatch = (int)(kSpatial / kVec);   // 65536
    const int vgA = wave * 32 + sub;
    const int vgB = vgA + 16;
    const int bA = vgA >> 16, rA = vgA & (vgPerBatch - 1);
    const int bB = vgB >> 16, rB = vgB & (vgPerBatch - 1);
    const size_t baseA = (size_t)bA * kInCh * kSpatial + (size_t)rA * kVec;
    const size_t baseB = (size_t)bB * kInCh * kSpatial + (size_t)rB * kVec;

    // ---- full pipeline after partial-ev accumulation (shared by A and B) ----
    auto process = [&](float (&ev)[kCls][kVec], size_t base) {
        // cross-chunk reduce (lanes l, l+16, l+32, l+48 share a voxel group)
        #pragma unroll
        for (int o = 0; o < kCls; ++o)
            #pragma unroll
            for (int v = 0; v < kVec; ++v) {
                float e = ev[o][v];
                e += __shfl_xor(e, 16, 64);
                e += __shfl_xor(e, 32, 64);
                ev[o][v] = e + s_bto[o];
            }

        // select this thread's vec element (v = chunk), compile-time indices only
        float evs[kCls];
        #pragma unroll
        for (int c = 0; c < kCls; ++c) {
            float e = ev[c][0];
            e = (chunk == 1) ? ev[c][1] : e;
            e = (chunk == 2) ? ev[c][2] : e;
            e = (chunk == 3) ? ev[c][3] : e;
            evs[c] = e;
        }

        // 20-proto evidence scan (one vec element per thread)
        float mkc[kCls];
        float mk5 = 1.0f;
        #pragma unroll
        for (int c = 0; c < kCls; ++c) mkc[c] = 0.0f;
        for (int k = 0; k < kProto; ++k) {
            float d = 0.0f;
            #pragma unroll
            for (int c = 0; c < kCls; ++c) {
                const float df = evs[c] - s_W[k][c];
                d += df * df;
            }
            d *= 0.5f;
            const float s  = s_ap[k] * __expf(-s_g2[k] * d);
            const float m5 = 1.0f - s;
            const float old5 = mk5;
            #pragma unroll
            for (int c = 0; c < kCls; ++c) {
                const float mc = s_U[k][c] * s;
                mkc[c] = mkc[c] * (mc + m5) + mc * old5;
            }
            mk5 = old5 * m5;
        }

        // normalize
        float K = mk5;
        #pragma unroll
        for (int c = 0; c < kCls; ++c) K += mkc[c];
        const float invK = 1.0f / K;
        float evid_s[kCls];
        #pragma unroll
        for (int c = 0; c < kCls; ++c) evid_s[c] = (mkc[c] + mk5) * invK;

        // redistribute: evid[c][v] lives on lane sub + v*16 (register-only bpermute)
        float evid[kCls][kVec];
        #pragma unroll
        for (int c = 0; c < kCls; ++c) {
            #pragma unroll
            for (int v = 0; v < kVec; ++v)
                evid[c][v] = lane_bcast(evid_s[c], sub + v * 16);
        }

        // back-projection: this thread's 16 output channels, nt stores
        #pragma unroll
        for (int j = 0; j < kChunk; ++j) {
            const int o = c0 + j;
            const float w0 = s_wf[o * kCls + 0];
            const float w1 = s_wf[o * kCls + 1];
            const float w2 = s_wf[o * kCls + 2];
            const float w3 = s_wf[o * kCls + 3];
            const float bo = s_bf[o];
            f32x4 acc;
            acc.x = bo + evid[0][0]*w0 + evid[1][0]*w1 + evid[2][0]*w2 + evid[3][0]*w3;
            acc.y = bo + evid[0][1]*w0 + evid[1][1]*w1 + evid[2][1]*w2 + evid[3][1]*w3;
            acc.z = bo + evid[0][2]*w0 + evid[1][2]*w1 + evid[2][2]*w2 + evid[3][2]*w3;
            acc.w = bo + evid[0][3]*w0 + evid[1][3]*w1 + evid[2][3]*w2 + evid[3][3]*w3;
            __builtin_nontemporal_store(acc, reinterpret_cast<f32x4*>(out + base + (size_t)o * kSpatial));
        }
    };

    // ---- phase A loads ----
    f32x4 xa[kChunk];
    #pragma unroll
    for (int j = 0; j < kChunk; ++j)
        xa[j] = *reinterpret_cast<const f32x4*>(x + baseA + (size_t)(c0 + j) * kSpatial);

    // ---- issue B loads while consuming A (A regs die as B regs fill) ----
    f32x4 xb[kChunk];
    float evA[kCls][kVec];
    #pragma unroll
    for (int o = 0; o < kCls; ++o)
        #pragma unroll
        for (int v = 0; v < kVec; ++v) evA[o][v] = 0.0f;

    #pragma unroll
    for (int j = 0; j < kChunk; ++j) {
        xb[j] = *reinterpret_cast<const f32x4*>(x + baseB + (size_t)(c0 + j) * kSpatial);
        const int c = c0 + j;
        #pragma unroll
        for (int o = 0; o < kCls; ++o) {
            const float w = s_wt[o * kInCh + c];
            evA[o][0] += xa[j].x * w;
            evA[o][1] += xa[j].y * w;
            evA[o][2] += xa[j].z * w;
            evA[o][3] += xa[j].w * w;
        }
    }

    // ---- full pipeline for A (B's 16 loads remain in flight underneath) ----
    process(evA, baseA);

    // ---- consume B, pipeline B ----
    float evB[kCls][kVec];
    #pragma unroll
    for (int o = 0; o < kCls; ++o)
        #pragma unroll
        for (int v = 0; v < kVec; ++v) evB[o][v] = 0.0f;

    #pragma unroll
    for (int j = 0; j < kChunk; ++j) {
        const int c = c0 + j;
        #pragma unroll
        for (int o = 0; o < kCls; ++o) {
            const float w = s_wt[o * kInCh + c];
            evB[o][0] += xb[j].x * w;
            evB[o][1] += xb[j].y * w;
            evB[o][2] += xb[j].z * w;
            evB[o][3] += xb[j].w * w;
        }
    }
    process(evB, baseB);
}

extern "C" void kernel_launch(void* const* d_in, const int* in_sizes, int n_in,
                              void* d_out, int out_size, void* d_ws, size_t ws_size,
                              hipStream_t stream) {
    const float* x      = (const float*)d_in[0];
    const float* w_to   = (const float*)d_in[1];
    const float* b_to   = (const float*)d_in[2];
    const float* w_from = (const float*)d_in[3];
    const float* b_from = (const float*)d_in[4];
    const float* Wm     = (const float*)d_in[5];
    const float* BETA   = (const float*)d_in[6];
    const float* alpha  = (const float*)d_in[7];
    const float* gamma  = (const float*)d_in[8];
    float* out = (float*)d_out;

    // 131072 voxel-groups, 32 per wave (2 phases x 16) -> 4096 waves -> 1024 blocks
    const int block = 256;
    const int grid  = 1024;
    evi_fused_kernel<<<grid, block, 0, stream>>>(x, w_to, b_to, w_from, b_from,
                                                 Wm, BETA, alpha, gamma, out);
}

// Round 5
// 297.941 us; speedup vs baseline: 1.0778x; 1.0778x over previous
//
#include <hip/hip_runtime.h>

// EVI fused kernel, round 5:
// - 4 threads co-own one float4 voxel group; each owns 16 of 64 channels.
// - Scan de-dup across chunk-threads (each thread scans one vec element).
// - Redistribution via __shfl_xor(16/32/48) + chunk-uniform XOR-swap cndmasks
//   (register-only; no variable-lane shuffle -> no 16KB LDS window).
// - 2 generations per thread (A, B). B's loads are issued AFTER A's projection
//   (xa dead -> regs reused), so B's 16 loads fly under A's scan + stores.
//   Peak live ~= xb[16] + evA + evid + misc ~= 115 VGPR < 128 cap. (R4 kept
//   xa+xb live -> 175 needed -> spill disaster: WRITE_SIZE 682 MB.)
// - Non-temporal stores keep `out` from evicting x out of the 256 MB L3.

constexpr int kInCh    = 64;
constexpr int kCls     = 4;
constexpr int kProto   = 20;
constexpr long kSpatial = 64L * 64L * 64L;   // 262144, D contiguous
constexpr int kVec     = 4;                   // float4 voxels per group
constexpr int kChunk   = 16;                  // channels per thread

typedef float f32x4 __attribute__((ext_vector_type(4)));

__global__ __launch_bounds__(256, 4) void evi_fused_kernel(
    const float* __restrict__ x,
    const float* __restrict__ w_to,    // (CLS, IN_CH)
    const float* __restrict__ b_to,    // (CLS,)
    const float* __restrict__ w_from,  // (IN_CH, CLS)
    const float* __restrict__ b_from,  // (IN_CH,)
    const float* __restrict__ Wm,      // (PROTO, CLS)
    const float* __restrict__ BETA,    // (PROTO, CLS)
    const float* __restrict__ alpha,   // (PROTO, 1)
    const float* __restrict__ gamma,   // (PROTO, 1)
    float* __restrict__ out)
{
    __shared__ float s_wt[kCls * kInCh];   // w_to[o][c]
    __shared__ float s_wf[kInCh * kCls];   // w_from[i][c]
    __shared__ float s_bf[kInCh];
    __shared__ float s_bto[kCls];
    __shared__ float s_W[kProto][kCls];
    __shared__ float s_U[kProto][kCls];
    __shared__ float s_ap[kProto];
    __shared__ float s_g2[kProto];

    const int t = threadIdx.x;

    // ---- stage weights / per-proto params into LDS (once per block) ----
    s_wt[t] = w_to[t];
    s_wf[t] = w_from[t];
    if (t < kInCh) s_bf[t] = b_from[t];
    if (t < kCls)  s_bto[t] = b_to[t];
    if (t < kProto) {
        float bsq[kCls];
        float sum = 0.f;
        #pragma unroll
        for (int c = 0; c < kCls; ++c) {
            const float bb = BETA[t * kCls + c];
            bsq[c] = bb * bb;
            sum += bsq[c];
        }
        const float inv = 1.0f / sum;
        #pragma unroll
        for (int c = 0; c < kCls; ++c) {
            s_U[t][c] = bsq[c] * inv;
            s_W[t][c] = Wm[t * kCls + c];
        }
        s_ap[t] = 0.99f / (1.0f + expf(-alpha[t]));
        const float g = gamma[t];
        s_g2[t] = g * g;
    }
    __syncthreads();

    // ---- lane decomposition: each wave handles 32 voxel groups (A:16, B:16) ----
    const int tid   = blockIdx.x * blockDim.x + t;
    const int wave  = tid >> 6;
    const int lane  = tid & 63;
    const int chunk = lane >> 4;                 // channels [chunk*16, chunk*16+16)
    const int sub   = lane & 15;
    const int c0    = chunk * kChunk;
    const bool cb1  = (chunk & 1) != 0;
    const bool cb2  = (chunk & 2) != 0;

    const int vgPerBatch = (int)(kSpatial / kVec);   // 65536
    const int vgA = wave * 32 + sub;
    const int vgB = vgA + 16;
    const int bA = vgA >> 16, rA = vgA & (vgPerBatch - 1);
    const int bB = vgB >> 16, rB = vgB & (vgPerBatch - 1);
    const size_t baseA = (size_t)bA * kInCh * kSpatial + (size_t)rA * kVec;
    const size_t baseB = (size_t)bB * kInCh * kSpatial + (size_t)rB * kVec;

    // ---- scan + normalize + redistribute + store (register-only cross-lane) ----
    auto process = [&](float (&ev)[kCls][kVec], size_t base) {
        // cross-chunk reduce (lanes l, l+16, l+32, l+48 share a voxel group)
        #pragma unroll
        for (int o = 0; o < kCls; ++o)
            #pragma unroll
            for (int v = 0; v < kVec; ++v) {
                float e = ev[o][v];
                e += __shfl_xor(e, 16, 64);
                e += __shfl_xor(e, 32, 64);
                ev[o][v] = e + s_bto[o];
            }

        // select this thread's vec element (v = chunk), compile-time indices only
        float evs[kCls];
        #pragma unroll
        for (int c = 0; c < kCls; ++c) {
            float e = ev[c][0];
            e = (chunk == 1) ? ev[c][1] : e;
            e = (chunk == 2) ? ev[c][2] : e;
            e = (chunk == 3) ? ev[c][3] : e;
            evs[c] = e;
        }

        // 20-proto evidence scan (one vec element per thread)
        float mkc[kCls];
        float mk5 = 1.0f;
        #pragma unroll
        for (int c = 0; c < kCls; ++c) mkc[c] = 0.0f;
        for (int k = 0; k < kProto; ++k) {
            float d = 0.0f;
            #pragma unroll
            for (int c = 0; c < kCls; ++c) {
                const float df = evs[c] - s_W[k][c];
                d += df * df;
            }
            d *= 0.5f;
            const float s  = s_ap[k] * __expf(-s_g2[k] * d);
            const float m5 = 1.0f - s;
            const float old5 = mk5;
            #pragma unroll
            for (int c = 0; c < kCls; ++c) {
                const float mc = s_U[k][c] * s;
                mkc[c] = mkc[c] * (mc + m5) + mc * old5;
            }
            mk5 = old5 * m5;
        }

        // normalize
        float K = mk5;
        #pragma unroll
        for (int c = 0; c < kCls; ++c) K += mkc[c];
        const float invK = 1.0f / K;
        float evid_s[kCls];
        #pragma unroll
        for (int c = 0; c < kCls; ++c) evid_s[c] = (mkc[c] + mk5) * invK;

        // redistribute: lane holds evid[chunk^m] as m-th value; XOR-swap into order.
        // evid[c][v] = gathered value with m = chunk ^ v.
        float evid[kCls][kVec];
        #pragma unroll
        for (int c = 0; c < kCls; ++c) {
            const float e0  = evid_s[c];
            const float s16 = __shfl_xor(e0, 16, 64);   // evid[chunk^1]
            const float s32 = __shfl_xor(e0, 32, 64);   // evid[chunk^2]
            const float s48 = __shfl_xor(s16, 32, 64);  // evid[chunk^3]
            // stage 1: chunk&1 -> swap (e0,s16), (s32,s48)
            const float a0 = cb1 ? s16 : e0;
            const float a1 = cb1 ? e0  : s16;
            const float a2 = cb1 ? s48 : s32;
            const float a3 = cb1 ? s32 : s48;
            // stage 2: chunk&2 -> swap (a0,a2), (a1,a3)
            evid[c][0] = cb2 ? a2 : a0;
            evid[c][1] = cb2 ? a3 : a1;
            evid[c][2] = cb2 ? a0 : a2;
            evid[c][3] = cb2 ? a1 : a3;
        }

        // back-projection: this thread's 16 output channels, nt stores
        #pragma unroll
        for (int j = 0; j < kChunk; ++j) {
            const int o = c0 + j;
            const float w0 = s_wf[o * kCls + 0];
            const float w1 = s_wf[o * kCls + 1];
            const float w2 = s_wf[o * kCls + 2];
            const float w3 = s_wf[o * kCls + 3];
            const float bo = s_bf[o];
            f32x4 acc;
            acc.x = bo + evid[0][0]*w0 + evid[1][0]*w1 + evid[2][0]*w2 + evid[3][0]*w3;
            acc.y = bo + evid[0][1]*w0 + evid[1][1]*w1 + evid[2][1]*w2 + evid[3][1]*w3;
            acc.z = bo + evid[0][2]*w0 + evid[1][2]*w1 + evid[2][2]*w2 + evid[3][2]*w3;
            acc.w = bo + evid[0][3]*w0 + evid[1][3]*w1 + evid[2][3]*w2 + evid[3][3]*w3;
            __builtin_nontemporal_store(acc, reinterpret_cast<f32x4*>(out + base + (size_t)o * kSpatial));
        }
    };

    // ================= generation A =================
    f32x4 xa[kChunk];
    #pragma unroll
    for (int j = 0; j < kChunk; ++j)
        xa[j] = *reinterpret_cast<const f32x4*>(x + baseA + (size_t)(c0 + j) * kSpatial);

    float evA[kCls][kVec];
    #pragma unroll
    for (int o = 0; o < kCls; ++o)
        #pragma unroll
        for (int v = 0; v < kVec; ++v) evA[o][v] = 0.0f;

    #pragma unroll
    for (int j = 0; j < kChunk; ++j) {           // consume xa -> xa dead after this
        const int c = c0 + j;
        #pragma unroll
        for (int o = 0; o < kCls; ++o) {
            const float w = s_wt[o * kInCh + c];
            evA[o][0] += xa[j].x * w;
            evA[o][1] += xa[j].y * w;
            evA[o][2] += xa[j].z * w;
            evA[o][3] += xa[j].w * w;
        }
    }

    // ---- issue generation-B loads now (registers of xa reusable) ----
    f32x4 xb[kChunk];
    #pragma unroll
    for (int j = 0; j < kChunk; ++j)
        xb[j] = *reinterpret_cast<const f32x4*>(x + baseB + (size_t)(c0 + j) * kSpatial);

    // ---- A's scan + stores run while B's loads are in flight ----
    process(evA, baseA);

    // ================= generation B =================
    float evB[kCls][kVec];
    #pragma unroll
    for (int o = 0; o < kCls; ++o)
        #pragma unroll
        for (int v = 0; v < kVec; ++v) evB[o][v] = 0.0f;

    #pragma unroll
    for (int j = 0; j < kChunk; ++j) {
        const int c = c0 + j;
        #pragma unroll
        for (int o = 0; o < kCls; ++o) {
            const float w = s_wt[o * kInCh + c];
            evB[o][0] += xb[j].x * w;
            evB[o][1] += xb[j].y * w;
            evB[o][2] += xb[j].z * w;
            evB[o][3] += xb[j].w * w;
        }
    }
    process(evB, baseB);
}

extern "C" void kernel_launch(void* const* d_in, const int* in_sizes, int n_in,
                              void* d_out, int out_size, void* d_ws, size_t ws_size,
                              hipStream_t stream) {
    const float* x      = (const float*)d_in[0];
    const float* w_to   = (const float*)d_in[1];
    const float* b_to   = (const float*)d_in[2];
    const float* w_from = (const float*)d_in[3];
    const float* b_from = (const float*)d_in[4];
    const float* Wm     = (const float*)d_in[5];
    const float* BETA   = (const float*)d_in[6];
    const float* alpha  = (const float*)d_in[7];
    const float* gamma  = (const float*)d_in[8];
    float* out = (float*)d_out;

    // 131072 voxel-groups, 32 per wave (2 gens x 16) -> 4096 waves -> 1024 blocks
    const int block = 256;
    const int grid  = 1024;
    evi_fused_kernel<<<grid, block, 0, stream>>>(x, w_to, b_to, w_from, b_from,
                                                 Wm, BETA, alpha, gamma, out);
}

// Round 6
// 52.440 us; speedup vs baseline: 6.1235x; 5.6815x over previous
//
#include <hip/hip_runtime.h>

// EVI fused kernel, round 6: clean single-generation, max per-wave MLP.
// - 4 threads co-own one float4 voxel group; each owns 16 of 64 channels.
// - Explicit load-all-16 into xa[] THEN consume: forces all 16 global loads
//   issued back-to-back (16 KB/wave in flight) before any FMA waits on them.
// - Scan de-dup across chunk-threads (each thread scans one vec element).
// - Redistribution via __shfl_xor(16/32) + chunk-uniform XOR-swap cndmasks
//   (register-only -> no LDS shuffle window, no variable-lane shuffle).
// - NO multi-generation pipelining (R4/R5 proved it spills: 650+ MB scratch).
// - __launch_bounds__(256) only: give the allocator headroom, no spills.
// - Non-temporal stores keep `out` from evicting x out of the 256 MB L3.

constexpr int kInCh    = 64;
constexpr int kCls     = 4;
constexpr int kProto   = 20;
constexpr long kSpatial = 64L * 64L * 64L;   // 262144, D contiguous
constexpr int kVec     = 4;                   // float4 voxels per group
constexpr int kChunk   = 16;                  // channels per thread

typedef float f32x4 __attribute__((ext_vector_type(4)));

__global__ __launch_bounds__(256) void evi_fused_kernel(
    const float* __restrict__ x,
    const float* __restrict__ w_to,    // (CLS, IN_CH)
    const float* __restrict__ b_to,    // (CLS,)
    const float* __restrict__ w_from,  // (IN_CH, CLS)
    const float* __restrict__ b_from,  // (IN_CH,)
    const float* __restrict__ Wm,      // (PROTO, CLS)
    const float* __restrict__ BETA,    // (PROTO, CLS)
    const float* __restrict__ alpha,   // (PROTO, 1)
    const float* __restrict__ gamma,   // (PROTO, 1)
    float* __restrict__ out)
{
    __shared__ float s_wt[kCls * kInCh];   // w_to[o][c]
    __shared__ float s_wf[kInCh * kCls];   // w_from[i][c]
    __shared__ float s_bf[kInCh];
    __shared__ float s_bto[kCls];
    __shared__ float s_W[kProto][kCls];
    __shared__ float s_U[kProto][kCls];
    __shared__ float s_ap[kProto];
    __shared__ float s_g2[kProto];

    const int t = threadIdx.x;

    // ---- stage weights / per-proto params into LDS (once per block) ----
    s_wt[t] = w_to[t];
    s_wf[t] = w_from[t];
    if (t < kInCh) s_bf[t] = b_from[t];
    if (t < kCls)  s_bto[t] = b_to[t];
    if (t < kProto) {
        float bsq[kCls];
        float sum = 0.f;
        #pragma unroll
        for (int c = 0; c < kCls; ++c) {
            const float bb = BETA[t * kCls + c];
            bsq[c] = bb * bb;
            sum += bsq[c];
        }
        const float inv = 1.0f / sum;
        #pragma unroll
        for (int c = 0; c < kCls; ++c) {
            s_U[t][c] = bsq[c] * inv;
            s_W[t][c] = Wm[t * kCls + c];
        }
        s_ap[t] = 0.99f / (1.0f + expf(-alpha[t]));
        const float g = gamma[t];
        s_g2[t] = g * g;
    }
    __syncthreads();

    // ---- lane decomposition ----
    const int tid   = blockIdx.x * blockDim.x + t;
    const int wave  = tid >> 6;
    const int lane  = tid & 63;
    const int chunk = lane >> 4;                 // channels [chunk*16, chunk*16+16)
    const int sub   = lane & 15;
    const int c0    = chunk * kChunk;
    const bool cb1  = (chunk & 1) != 0;
    const bool cb2  = (chunk & 2) != 0;

    const int vgPerBatch = (int)(kSpatial / kVec);   // 65536
    const int vg = wave * 16 + sub;                  // [0, 131072)
    const int b = vg >> 16;
    const int r = vg & (vgPerBatch - 1);
    const size_t base = (size_t)b * kInCh * kSpatial + (size_t)r * kVec;

    // ---- issue ALL 16 loads first (back-to-back, max MLP) ----
    f32x4 xa[kChunk];
    #pragma unroll
    for (int j = 0; j < kChunk; ++j)
        xa[j] = *reinterpret_cast<const f32x4*>(x + base + (size_t)(c0 + j) * kSpatial);

    // ---- consume: partial ev over this thread's 16 channels ----
    float ev[kCls][kVec];
    #pragma unroll
    for (int o = 0; o < kCls; ++o)
        #pragma unroll
        for (int v = 0; v < kVec; ++v) ev[o][v] = 0.0f;

    #pragma unroll
    for (int j = 0; j < kChunk; ++j) {
        const int c = c0 + j;
        #pragma unroll
        for (int o = 0; o < kCls; ++o) {
            const float w = s_wt[o * kInCh + c];
            ev[o][0] += xa[j].x * w;
            ev[o][1] += xa[j].y * w;
            ev[o][2] += xa[j].z * w;
            ev[o][3] += xa[j].w * w;
        }
    }

    // ---- cross-chunk reduce (lanes l, l+16, l+32, l+48 share a voxel group) ----
    #pragma unroll
    for (int o = 0; o < kCls; ++o)
        #pragma unroll
        for (int v = 0; v < kVec; ++v) {
            float e = ev[o][v];
            e += __shfl_xor(e, 16, 64);
            e += __shfl_xor(e, 32, 64);
            ev[o][v] = e + s_bto[o];
        }

    // ---- select this thread's vec element (v = chunk), compile-time indices ----
    float evs[kCls];
    #pragma unroll
    for (int c = 0; c < kCls; ++c) {
        float e = ev[c][0];
        e = (chunk == 1) ? ev[c][1] : e;
        e = (chunk == 2) ? ev[c][2] : e;
        e = (chunk == 3) ? ev[c][3] : e;
        evs[c] = e;
    }

    // ---- 20-proto evidence scan (one vec element per thread) ----
    float mkc[kCls];
    float mk5 = 1.0f;
    #pragma unroll
    for (int c = 0; c < kCls; ++c) mkc[c] = 0.0f;
    for (int k = 0; k < kProto; ++k) {
        float d = 0.0f;
        #pragma unroll
        for (int c = 0; c < kCls; ++c) {
            const float df = evs[c] - s_W[k][c];
            d += df * df;
        }
        d *= 0.5f;
        const float s  = s_ap[k] * __expf(-s_g2[k] * d);
        const float m5 = 1.0f - s;
        const float old5 = mk5;
        #pragma unroll
        for (int c = 0; c < kCls; ++c) {
            const float mc = s_U[k][c] * s;
            mkc[c] = mkc[c] * (mc + m5) + mc * old5;
        }
        mk5 = old5 * m5;
    }

    // ---- normalize ----
    float K = mk5;
    #pragma unroll
    for (int c = 0; c < kCls; ++c) K += mkc[c];
    const float invK = 1.0f / K;
    float evid_s[kCls];
    #pragma unroll
    for (int c = 0; c < kCls; ++c) evid_s[c] = (mkc[c] + mk5) * invK;

    // ---- redistribute via xor-shuffles + chunk-uniform XOR-swaps ----
    // lane holds evid of vec element `chunk`; evid[c][v] needs element v.
    float evid[kCls][kVec];
    #pragma unroll
    for (int c = 0; c < kCls; ++c) {
        const float e0  = evid_s[c];
        const float s16 = __shfl_xor(e0, 16, 64);   // element chunk^1
        const float s32 = __shfl_xor(e0, 32, 64);   // element chunk^2
        const float s48 = __shfl_xor(s16, 32, 64);  // element chunk^3
        // stage 1: chunk&1 -> swap (e0,s16), (s32,s48)
        const float a0 = cb1 ? s16 : e0;
        const float a1 = cb1 ? e0  : s16;
        const float a2 = cb1 ? s48 : s32;
        const float a3 = cb1 ? s32 : s48;
        // stage 2: chunk&2 -> swap (a0,a2), (a1,a3)
        evid[c][0] = cb2 ? a2 : a0;
        evid[c][1] = cb2 ? a3 : a1;
        evid[c][2] = cb2 ? a0 : a2;
        evid[c][3] = cb2 ? a1 : a3;
    }

    // ---- back-projection: this thread's 16 output channels, nt stores ----
    #pragma unroll
    for (int j = 0; j < kChunk; ++j) {
        const int o = c0 + j;
        const float w0 = s_wf[o * kCls + 0];
        const float w1 = s_wf[o * kCls + 1];
        const float w2 = s_wf[o * kCls + 2];
        const float w3 = s_wf[o * kCls + 3];
        const float bo = s_bf[o];
        f32x4 acc;
        acc.x = bo + evid[0][0]*w0 + evid[1][0]*w1 + evid[2][0]*w2 + evid[3][0]*w3;
        acc.y = bo + evid[0][1]*w0 + evid[1][1]*w1 + evid[2][1]*w2 + evid[3][1]*w3;
        acc.z = bo + evid[0][2]*w0 + evid[1][2]*w1 + evid[2][2]*w2 + evid[3][2]*w3;
        acc.w = bo + evid[0][3]*w0 + evid[1][3]*w1 + evid[2][3]*w2 + evid[3][3]*w3;
        __builtin_nontemporal_store(acc, reinterpret_cast<f32x4*>(out + base + (size_t)o * kSpatial));
    }
}

extern "C" void kernel_launch(void* const* d_in, const int* in_sizes, int n_in,
                              void* d_out, int out_size, void* d_ws, size_t ws_size,
                              hipStream_t stream) {
    const float* x      = (const float*)d_in[0];
    const float* w_to   = (const float*)d_in[1];
    const float* b_to   = (const float*)d_in[2];
    const float* w_from = (const float*)d_in[3];
    const float* b_from = (const float*)d_in[4];
    const float* Wm     = (const float*)d_in[5];
    const float* BETA   = (const float*)d_in[6];
    const float* alpha  = (const float*)d_in[7];
    const float* gamma  = (const float*)d_in[8];
    float* out = (float*)d_out;

    // 131072 voxel-groups x 4 chunk-threads = 524288 threads -> 2048 blocks
    const int block = 256;
    const int grid  = 2048;
    evi_fused_kernel<<<grid, block, 0, stream>>>(x, w_to, b_to, w_from, b_from,
                                                 Wm, BETA, alpha, gamma, out);
}